// Round 5
// baseline (3098.748 us; speedup 1.0000x reference)
//
#include <hip/hip_runtime.h>
#include <hip/hip_bf16.h>

// Model dims
#define NN 2048
#define DS 64
#define DI 256
#define DV 64
#define KK 512
#define HH 4
#define HD 16
#define BB 2
#define TT 4
#define DCAT 192
#define NB 256          // grid blocks (1 per CU; co-residency safe)

typedef unsigned long long ull;

__device__ __forceinline__ float wave_sum(float v) {
#pragma unroll
    for (int o = 32; o > 0; o >>= 1) v += __shfl_xor(v, o);
    return v;
}
__device__ __forceinline__ float wave_max(float v) {
#pragma unroll
    for (int o = 32; o > 0; o >>= 1) v = fmaxf(v, __shfl_xor(v, o));
    return v;
}
__device__ __forceinline__ unsigned enc_f(float f) {
    unsigned u = __float_as_uint(f);
    return (u & 0x80000000u) ? ~u : (u | 0x80000000u);
}

// grid-wide barrier: ROCm cooperative-groups pattern (device-scope fence +
// agent atomics -> valid across non-coherent per-XCD L2s).
__device__ __forceinline__ void gbar(unsigned* cnt, unsigned* gen) {
    __syncthreads();
    if (threadIdx.x == 0) {
        unsigned g = __hip_atomic_load(gen, __ATOMIC_RELAXED, __HIP_MEMORY_SCOPE_AGENT);
        __threadfence();
        unsigned a = __hip_atomic_fetch_add(cnt, 1u, __ATOMIC_ACQ_REL, __HIP_MEMORY_SCOPE_AGENT);
        if (a == (unsigned)(NB - 1)) {
            __hip_atomic_store(cnt, 0u, __ATOMIC_RELAXED, __HIP_MEMORY_SCOPE_AGENT);
            __hip_atomic_fetch_add(gen, 1u, __ATOMIC_RELEASE, __HIP_MEMORY_SCOPE_AGENT);
        } else {
            while (__hip_atomic_load(gen, __ATOMIC_ACQUIRE, __HIP_MEMORY_SCOPE_AGENT) == g)
                __builtin_amdgcn_s_sleep(2);
        }
        __threadfence();
    }
    __syncthreads();
}

__global__ __launch_bounds__(256) void k_mega(
    const float* __restrict__ x, const float* __restrict__ W_in,
    const float* __restrict__ norm_w, const float* __restrict__ Wg,
    const float* __restrict__ Wout, const float* __restrict__ W_gate,
    const float* __restrict__ W_vote, const float* __restrict__ attn_in_w,
    const float* __restrict__ attn_out_w, const float* __restrict__ Wfs,
    const float* __restrict__ Wfsh, const float* __restrict__ query,
    const float* __restrict__ onw, const float* __restrict__ W_out,
    float* __restrict__ out,
    float* __restrict__ h, float* __restrict__ gate, float* __restrict__ xproj,
    int* __restrict__ col2slot, int* __restrict__ act_idx,
    float* __restrict__ u_g, float* __restrict__ part,
    float* __restrict__ qh, float* __restrict__ kh, float* __restrict__ vh,
    float* __restrict__ m_raw, float* __restrict__ fsm, float* __restrict__ fshm,
    float* __restrict__ ppool, float* __restrict__ psum, float* __restrict__ pmax,
    unsigned* __restrict__ bar)
{
    __shared__ ull smem_u[4352];          // 34816 bytes, max stage need 34048
    char* smem = (char*)smem_u;
    const int blk = blockIdx.x, tid = threadIdx.x;
    unsigned* cnt = bar;
    unsigned* gen = bar + 16;             // separate cache line

    for (int t = 0; t <= TT; ++t) {
        // ================= S1: topk(t) || xproj(t) || out(t-1) || h-zero(t==0)
        if (t < TT && blk < 2) {
            int b = blk;
            if (t == 0) {                 // h==0 -> gate==0 -> stable top_k = 0..K-1
                for (int i = tid; i < NN; i += 256) col2slot[b * NN + i] = (i < KK) ? i : -1;
                for (int i = tid; i < KK; i += 256) act_idx[b * KK + i] = i;
            } else {
                ull* keys = (ull*)smem;                       // 16384
                unsigned* hist = (unsigned*)(smem + 16384);   // 1024
                unsigned* suf  = (unsigned*)(smem + 17408);   // 1024
                ull* pref_sh   = (ull*)(smem + 18432);
                int* need_sh   = (int*)(smem + 18440);
                unsigned* ccnt = (unsigned*)(smem + 18444);
                if (tid == 0) *ccnt = 0;
                for (int i = tid; i < NN; i += 256) {
                    keys[i] = ((ull)enc_f(gate[b * NN + i]) << 11) | (unsigned)(NN - 1 - i);
                    col2slot[b * NN + i] = -1;
                }
                ull prefix = 0, pmask = 0;
                int need = KK;
                for (int shift = 40; shift >= 0; shift -= 8) {
                    hist[tid] = 0;
                    __syncthreads();
                    for (int i = tid; i < NN; i += 256) {
                        ull k = keys[i];
                        if ((k & pmask) == prefix)
                            atomicAdd(&hist[(unsigned)((k >> shift) & 255)], 1u);
                    }
                    __syncthreads();
                    suf[tid] = hist[tid];
                    __syncthreads();
                    for (int s = 1; s < 256; s <<= 1) {       // suffix sum
                        unsigned v = (tid + s < 256) ? suf[tid + s] : 0u;
                        __syncthreads();
                        suf[tid] += v;
                        __syncthreads();
                    }
                    {
                        unsigned here = suf[tid];
                        unsigned above = (tid == 255) ? 0u : suf[tid + 1];
                        if (here >= (unsigned)need && above < (unsigned)need) {
                            *pref_sh = prefix | ((ull)tid << shift);
                            *need_sh = need - (int)above;
                        }
                    }
                    __syncthreads();
                    prefix = *pref_sh; need = *need_sh; pmask |= (0xFFull << shift);
                    __syncthreads();
                }
                for (int i = tid; i < NN; i += 256) {
                    ull k = keys[i];
                    if (k >= prefix) {
                        unsigned p = atomicAdd(ccnt, 1u);
                        int n = NN - 1 - (int)(k & 2047ull);
                        act_idx[b * KK + p] = n;
                        col2slot[b * NN + n] = (int)p;
                    }
                }
            }
        } else if (t < TT && blk < 4) {   // xproj
            int b = blk - 2;
            int r = tid >> 2, q = tid & 3;
            const float* xp = x + (b * TT + t) * DI + q * 64;
            const float* wr = W_in + r * DI + q * 64;
            float a = 0.f;
#pragma unroll
            for (int i = 0; i < 64; i++) a += xp[i] * wr[i];
            a += __shfl_xor(a, 1); a += __shfl_xor(a, 2);
            if (q == 0) xproj[b * DS + r] = a;
        }
        if (t > 0 && blk >= 4 && blk < 6) {   // out(t-1)
            int b = blk - 4;
            float* pn = (float*)(smem + 20480);
            if (tid < 64) {
                int d = tid;
                float gm = -1e30f;
                for (int i = 0; i < 64; i++) gm = fmaxf(gm, pmax[b * 64 + i]);
                float s = 0.f, v = 0.f;
                for (int i = 0; i < 64; i++) {
                    float e = __expf(pmax[b * 64 + i] - gm);
                    s += psum[b * 64 + i] * e;
                    v += ppool[(b * 64 + i) * 64 + d] * e;
                }
                float val = v / s;
                float ss = wave_sum(val * val);
                float rs = rsqrtf(ss * (1.0f / DS) + 1e-6f);
                pn[d] = onw[d] * val * rs;
            }
            __syncthreads();
            {
                int o = tid;
                const float* wr = W_out + o * DS;
                float a = 0.f;
#pragma unroll
                for (int d = 0; d < DS; d++) a += pn[d] * wr[d];
                out[(b * TT + (t - 1)) * DI + o] = a;
            }
        }
        if (t == 0 && blk >= 6) {             // zero h
            float4 z4 = {0.f, 0.f, 0.f, 0.f};
            float4* h4 = (float4*)h;
            for (int i = (blk - 6) * 256 + tid; i < BB * NN * DS / 4; i += 250 * 256) h4[i] = z4;
        }
        if (t == TT) break;
        gbar(cnt, gen);

        // ================= S2: core_a (all 256 blocks)
        {
            float* zt  = (float*)smem;              // 32768
            float* ssq = (float*)(smem + 32768);    // 1024
            float* rsb = (float*)(smem + 33792);    // 256
            int cg = blk >> 4, og = blk & 15;
            int c = tid & 63;
            int seg = __builtin_amdgcn_readfirstlane(tid >> 6);
            int b = cg >> 3, sbase = (cg & 7) * 64;
            int n = act_idx[b * KK + sbase + c];
            float vals[32];
            float sq = 0.f;
            if (seg < 2) {
                const float* hp = h + ((size_t)(b * NN + n)) * DS + seg * 32;
#pragma unroll
                for (int i = 0; i < 32; i++) { float v = hp[i]; vals[i] = v; sq += v * v; }
            } else {
                const float* xp = xproj + b * DS + (seg - 2) * 32;
#pragma unroll
                for (int i = 0; i < 32; i++) { float v = xp[i]; vals[i] = v; sq += v * v; }
            }
            ssq[seg * 64 + c] = sq;
            __syncthreads();
            if (tid < 64) {
                float s = ssq[tid] + ssq[64 + tid] + ssq[128 + tid] + ssq[192 + tid];
                rsb[tid] = rsqrtf(s * (1.0f / DCAT) + 1e-6f);
            }
            __syncthreads();
            {
                float rs = rsb[c];
#pragma unroll
                for (int i = 0; i < 32; i++) {
                    int d = seg * 32 + i;
                    zt[d * 64 + c] = norm_w[d] * vals[i] * rs;
                }
            }
            __syncthreads();
            float z[128];
#pragma unroll
            for (int d = 0; d < 128; d++) z[d] = zt[d * 64 + c];
            int rbase = og * 16 + seg * 4;
            float ga[4];
#pragma unroll
            for (int r = 0; r < 4; r++) {
                const float* wr = Wg + (rbase + r) * DCAT;    // uniform -> s_load
                float acc = 0.f;
#pragma unroll
                for (int d = 0; d < 128; d++) acc += z[d] * wr[d];
                ga[r] = acc;
            }
            int gcol = cg * 64 + c;
#pragma unroll
            for (int r = 0; r < 4; r++) {
                const float* wr = Wg + (256 + rbase + r) * DCAT;
                float bacc = 0.f;
#pragma unroll
                for (int d = 0; d < 128; d++) bacc += z[d] * wr[d];
                float uu = ga[r] * (bacc / (1.f + expf(-bacc)));
                u_g[(rbase + r) * 1024 + gcol] = uu;
            }
        }
        gbar(cnt, gen);

        // ================= S3: hupd (blocks 0..63)
        if (blk < 64) {
            int cg = blk >> 2, kc = blk & 3;
            int c = tid & 63, w = tid >> 6;
            int gcol = cg * 64 + c;
            float uu[64];
#pragma unroll
            for (int i = 0; i < 64; i++) uu[i] = u_g[(kc * 64 + i) * 1024 + gcol];
#pragma unroll
            for (int oi = 0; oi < 16; oi++) {
                int o = w * 16 + oi;
                const float* wr = Wout + o * 256 + kc * 64;   // uniform
                float acc = 0.f;
#pragma unroll
                for (int i = 0; i < 64; i++) acc += uu[i] * wr[i];
                part[(kc * 64 + o) * 1024 + gcol] = acc;
            }
        }
        gbar(cnt, gen);

        // ================= S4: vqkv (blocks 0..31)
        if (blk < 32) {
            float* hn = (float*)smem;               // 8192
            float* vv = (float*)(smem + 8192);      // 8192
            int* an = (int*)(smem + 16384);         // 128
            int b = blk >> 4;
            int sbase = (blk & 15) * 32;
            int w = __builtin_amdgcn_readfirstlane(tid >> 6);
            int l = tid & 63;
            int c = l & 31, sub = l >> 5;
            if (tid < 32) an[tid] = act_idx[b * KK + sbase + tid];
            __syncthreads();
            {
                int cc = tid & 31, o0 = tid >> 5;
                int gcol = b * KK + sbase + cc;
#pragma unroll
                for (int kk = 0; kk < 8; kk++) {
                    int o = o0 + kk * 8;
                    float s = part[o * 1024 + gcol] + part[(64 + o) * 1024 + gcol]
                            + part[(128 + o) * 1024 + gcol] + part[(192 + o) * 1024 + gcol];
                    size_t hidx = ((size_t)(b * NN + an[cc])) * DS + o;
                    float nh = h[hidx] + s;
                    h[hidx] = nh;
                    hn[o * 32 + cc] = nh;
                }
            }
            __syncthreads();
            float hh[32];
#pragma unroll
            for (int i = 0; i < 32; i++) hh[i] = hn[(sub * 32 + i) * 32 + c];
#pragma unroll 4
            for (int oi = 0; oi < 16; oi++) {
                int o = w * 16 + oi;
                const float* wr = W_vote + o * 64 + sub * 32;
                float a = 0.f;
#pragma unroll
                for (int i = 0; i < 32; i++) a += hh[i] * wr[i];
                a += __shfl_xor(a, 32);
                if (sub == 0) vv[o * 32 + c] = a;
            }
            __syncthreads();
            float vq[32];
#pragma unroll
            for (int i = 0; i < 32; i++) vq[i] = vv[(sub * 32 + i) * 32 + c];
            int slot = sbase + c;
#pragma unroll 4
            for (int oi = 0; oi < 48; oi++) {
                int r = w * 48 + oi;
                const float* wr = attn_in_w + r * 64 + sub * 32;
                float a = 0.f;
#pragma unroll
                for (int i = 0; i < 32; i++) a += vq[i] * wr[i];
                a += __shfl_xor(a, 32);
                if (sub == 0) {
                    if (r < 64) {
                        qh[((b * HH + (r >> 4)) * KK + slot) * HD + (r & 15)] = a;
                    } else if (r < 128) {
                        int rr = r - 64;
                        kh[((b * HH + (rr >> 4)) * HD + (rr & 15)) * KK + slot] = a;
                    } else {
                        int rr = r - 128;
                        vh[((b * HH + (rr >> 4)) * HD + (rr & 15)) * KK + slot] = a;
                    }
                }
            }
        }
        gbar(cnt, gen);

        // ================= S5: attention (all blocks; wave = 4 queries of one bh)
        {
            int w = blk * 4 + (tid >> 6);
            int lane = tid & 63;
            int bh = w >> 7;
            int qbase = (w & 127) * 4;
            const float* kp = kh + bh * HD * KK;
            const float* vp = vh + bh * HD * KK;
            for (int qi = 0; qi < 4; qi++) {
                int qs = qbase + qi;
                const float* qp = qh + (bh * KK + qs) * HD;
                float q[HD];
#pragma unroll
                for (int d = 0; d < HD; d++) q[d] = qp[d];
                float lg[8]; float mx = -1e30f;
#pragma unroll
                for (int i = 0; i < 8; i++) {
                    int slot = i * 64 + lane;
                    float a = 0.f;
#pragma unroll
                    for (int d = 0; d < HD; d++) a += q[d] * kp[d * KK + slot];
                    lg[i] = a * 0.25f;
                    mx = fmaxf(mx, lg[i]);
                }
                mx = wave_max(mx);
                float p[8]; float sum = 0.f;
#pragma unroll
                for (int i = 0; i < 8; i++) { p[i] = __expf(lg[i] - mx); sum += p[i]; }
                sum = wave_sum(sum);
                float inv = 1.0f / sum;
                float acc[HD];
#pragma unroll
                for (int d = 0; d < HD; d++) acc[d] = 0.f;
#pragma unroll
                for (int i = 0; i < 8; i++) {
                    int slot = i * 64 + lane;
                    float pi = p[i];
#pragma unroll
                    for (int d = 0; d < HD; d++) acc[d] += pi * vp[d * KK + slot];
                }
#pragma unroll
                for (int d = 0; d < HD; d++) acc[d] = wave_sum(acc[d]) * inv;
                if (lane == 0) {
                    int b = bh >> 2, head = bh & 3;
#pragma unroll
                    for (int d = 0; d < HD; d++)
                        m_raw[(b * DV + head * HD + d) * KK + qs] = acc[d];
                }
            }
        }
        gbar(cnt, gen);

        // ================= S6: film (blocks 0..31 active; 32..33 mean)
        if (blk < 32) {
            float* mt  = (float*)smem;              // [64][32] 8192
            float* mot = (float*)(smem + 8192);     // [64][32] 8192
            float* sct = (float*)(smem + 16384);    // [32][65] 8320
            float* sht = (float*)(smem + 24704);    // [32][65] 8320
            int* an    = (int*)(smem + 33024);      // 128
            int b = blk >> 4;
            int sbase = (blk & 15) * 32;
            int w = __builtin_amdgcn_readfirstlane(tid >> 6);
            int lane = tid & 63;
            int s = lane & 31, half = lane >> 5;
            if (tid < 32) an[tid] = act_idx[b * KK + sbase + tid];
            for (int idx = tid; idx < 2048; idx += 256) {
                int d = idx >> 5, ss = idx & 31;
                mt[d * 32 + ss] = m_raw[(b * DV + d) * KK + sbase + ss];
            }
            __syncthreads();
#pragma unroll 4
            for (int oi = 0; oi < 16; oi++) {
                int o = w * 16 + oi;
                const float* wr = attn_out_w + o * DV + half * 32;   // uniform
                float a = 0.f;
#pragma unroll
                for (int e = 0; e < 32; e++) a += mt[(half * 32 + e) * 32 + s] * wr[e];
                a += __shfl_xor(a, 32);
                if (half == 0) mot[o * 32 + s] = a;
            }
            __syncthreads();
#pragma unroll 4
            for (int oi = 0; oi < 16; oi++) {
                int o = w * 16 + oi;
                const float* ws_ = Wfs + o * DV + half * 32;
                const float* wh_ = Wfsh + o * DV + half * 32;
                float sc = 0.f, sh = 0.f;
#pragma unroll
                for (int e = 0; e < 32; e++) {
                    float zz = mot[(half * 32 + e) * 32 + s];
                    sc += ws_[e] * zz; sh += wh_[e] * zz;
                }
                sc += __shfl_xor(sc, 32); sh += __shfl_xor(sh, 32);
                if (half == 0) { sct[s * 65 + o] = tanhf(sc); sht[s * 65 + o] = sh; }
            }
            __syncthreads();
            for (int idx = tid; idx < 2048; idx += 256) {
                int o = idx & 63, ss = idx >> 6;
                size_t hix = ((size_t)(b * NN + an[ss])) * DS + o;
                h[hix] = h[hix] * (1.f + sct[ss * 65 + o]) + sht[ss * 65 + o];
            }
        } else if (blk < 34) {
            int b = blk - 32;
            float* partm = (float*)smem;            // 1024
            float* mr = (float*)(smem + 1024);      // 256
            float* mo2 = (float*)(smem + 1280);     // 256
            int w = tid >> 6, lane = tid & 63;
            float macc[64];
#pragma unroll
            for (int d = 0; d < 64; d++) macc[d] = 0.f;
            for (int s = tid; s < KK; s += 256) {
#pragma unroll
                for (int d = 0; d < 64; d++) macc[d] += vh[(b * DV + d) * KK + s];
            }
#pragma unroll
            for (int d = 0; d < 64; d++) macc[d] = wave_sum(macc[d]);
            if (lane == 0) {
#pragma unroll
                for (int d = 0; d < 64; d++) partm[w * 64 + d] = macc[d];
            }
            __syncthreads();
            if (tid < 64)
                mr[tid] = (partm[tid] + partm[64 + tid] + partm[128 + tid] + partm[192 + tid]) * (1.0f / KK);
            __syncthreads();
            if (tid < 64) {
                const float* wo = attn_out_w + tid * DV;
                float a = 0.f;
#pragma unroll
                for (int e = 0; e < 64; e++) a += mr[e] * wo[e];
                mo2[tid] = a;
            }
            __syncthreads();
            if (tid < 64) {
                const float* ws_ = Wfs + tid * DV;
                const float* wh_ = Wfsh + tid * DV;
                float sc = 0.f, sh = 0.f;
#pragma unroll
                for (int e = 0; e < 64; e++) { float zz = mo2[e]; sc += ws_[e] * zz; sh += wh_[e] * zz; }
                fsm[b * DS + tid] = tanhf(sc);
                fshm[b * DS + tid] = sh;
            }
        }
        gbar(cnt, gen);

        // ================= S7: pool2 (blocks 0..127)
        if (blk < 128) {
            float* wvecs = (float*)smem;            // 4*64*4 = 1024
            float* wms = (float*)(smem + 1024);
            float* wss = (float*)(smem + 1040);
            int b = blk >> 6;
            int base = (blk & 63) * 32;
            int w = tid >> 6, lane = tid & 63;
            float fs = fsm[b * DS + lane], fh = fshm[b * DS + lane];
            float qv = query[lane] * 0.125f, wg = W_gate[lane];
            float wm = -1e30f, sw = 0.f, vec = 0.f;
#pragma unroll
            for (int ci = 0; ci < 8; ci++) {
                int n = base + w * 8 + ci;
                size_t idx = ((size_t)(b * NN + n)) * DS + lane;
                float hv = h[idx];
                int slot = col2slot[b * NN + n];
                if (slot < 0) { hv = hv * (1.f + fs) + fh; h[idx] = hv; }
                float lg = wave_sum(qv * hv);
                float gt = wave_sum(wg * hv);
                if (lane == 0) gate[b * NN + n] = gt;
                float nm = fmaxf(wm, lg);
                float scale = __expf(wm - nm);
                float e = __expf(lg - nm);
                sw = sw * scale + e;
                vec = vec * scale + e * hv;
                wm = nm;
            }
            wvecs[w * 64 + lane] = vec;
            if (lane == 0) { wms[w] = wm; wss[w] = sw; }
            __syncthreads();
            if (tid < 64) {
                float m4 = fmaxf(fmaxf(wms[0], wms[1]), fmaxf(wms[2], wms[3]));
                float ss = 0.f, v = 0.f;
#pragma unroll
                for (int ww = 0; ww < 4; ww++) {
                    float e = __expf(wms[ww] - m4);
                    ss += wss[ww] * e;
                    v += wvecs[ww * 64 + tid] * e;
                }
                ppool[blk * 64 + tid] = v;
                if (tid == 0) { psum[blk] = ss; pmax[blk] = m4; }
            }
        }
        gbar(cnt, gen);
    }
}

// ----------------------------------------------------------------
extern "C" void kernel_launch(void* const* d_in, const int* in_sizes, int n_in,
                              void* d_out, int out_size, void* d_ws, size_t ws_size,
                              hipStream_t stream)
{
    const float* x          = (const float*)d_in[0];
    const float* W_in       = (const float*)d_in[1];
    const float* core_norm_w= (const float*)d_in[2];
    const float* core_Wg    = (const float*)d_in[3];
    const float* core_Wout  = (const float*)d_in[4];
    const float* W_gate     = (const float*)d_in[5];
    const float* W_vote     = (const float*)d_in[6];
    const float* attn_in_w  = (const float*)d_in[7];
    const float* attn_out_w = (const float*)d_in[8];
    const float* Wfs        = (const float*)d_in[9];
    const float* Wfsh       = (const float*)d_in[10];
    const float* query      = (const float*)d_in[11];
    const float* onw        = (const float*)d_in[12];
    const float* W_out      = (const float*)d_in[13];
    float* out = (float*)d_out;

    float* ws = (float*)d_ws;
    float* h        = ws;                              // 262144
    float* gate     = h + (size_t)BB * NN * DS;        // 4096
    float* xproj    = gate + BB * NN;                  // 128
    int*   col2slot = (int*)(xproj + BB * DS);         // 4096
    int*   act_idx  = col2slot + BB * NN;              // 1024
    float* u_g      = (float*)(act_idx + BB * KK);     // 262144
    float* part     = u_g + 256 * 1024;                // 262144
    float* qh       = part + 256 * 1024;               // 65536
    float* kh       = qh + BB * HH * KK * HD;
    float* vh       = kh + BB * HH * KK * HD;
    float* m_raw    = vh + BB * HH * KK * HD;          // 65536
    float* fsm      = m_raw + BB * DV * KK;            // 128
    float* fshm     = fsm + BB * DS;                   // 128
    float* ppool    = fshm + BB * DS;                  // 8192
    float* psum     = ppool + 128 * 64;                // 128
    float* pmax     = psum + 128;                      // 128
    unsigned* bar   = (unsigned*)(pmax + 128);         // 32 u32 (128 B)

    hipMemsetAsync(bar, 0, 128, stream);

    k_mega<<<NB, 256, 0, stream>>>(
        x, W_in, core_norm_w, core_Wg, core_Wout, W_gate, W_vote,
        attn_in_w, attn_out_w, Wfs, Wfsh, query, onw, W_out, out,
        h, gate, xproj, col2slot, act_idx, u_g, part, qh, kh, vh,
        m_raw, fsm, fshm, ppool, psum, pmax, bar);
}

// Round 6
// 422.215 us; speedup vs baseline: 7.3393x; 7.3393x over previous
//
#include <hip/hip_runtime.h>
#include <hip/hip_bf16.h>

// Model dims
#define NN 2048
#define DS 64
#define DI 256
#define DV 64
#define KK 512
#define HH 4
#define HD 16
#define BB 2
#define TT 4
#define DCAT 192

typedef unsigned long long ull;

__device__ __forceinline__ float wave_sum(float v) {
#pragma unroll
    for (int o = 32; o > 0; o >>= 1) v += __shfl_xor(v, o);
    return v;
}
__device__ __forceinline__ float wave_max(float v) {
#pragma unroll
    for (int o = 32; o > 0; o >>= 1) v = fmaxf(v, __shfl_xor(v, o));
    return v;
}
__device__ __forceinline__ unsigned enc_f(float f) {
    unsigned u = __float_as_uint(f);
    return (u & 0x80000000u) ? ~u : (u | 0x80000000u);
}

// ---------------------------------------------------------------- K1: head kernel
// blocks 0-1: radix-select top-k (t<TT) + xproj(t).  blocks 2-3: out(t-1).
// t==0: h==0 -> gate==0 -> stable top_k = indices 0..K-1 (fast path).
__global__ __launch_bounds__(256) void k_head(
    const float* __restrict__ gate, const float* __restrict__ x,
    const float* __restrict__ W_in, int* __restrict__ col2slot,
    int* __restrict__ act_idx, float* __restrict__ xproj,
    const float* __restrict__ ppool, const float* __restrict__ psum,
    const float* __restrict__ pmax, const float* __restrict__ onw,
    const float* __restrict__ W_out, float* __restrict__ out, int t)
{
    __shared__ char smem[20992];
    int blk = blockIdx.x, tid = threadIdx.x;
    if (blk < 2) {
        if (t >= TT) return;
        int b = blk;
        {   // xproj: x_t @ W_in.T  (4 lanes per output row)
            int r = tid >> 2, q = tid & 3;
            const float* xp = x + (b * TT + t) * DI + q * 64;
            const float* wr = W_in + r * DI + q * 64;
            float a = 0.f;
#pragma unroll
            for (int i = 0; i < 64; i++) a += xp[i] * wr[i];
            a += __shfl_xor(a, 1); a += __shfl_xor(a, 2);
            if (q == 0) xproj[b * DS + r] = a;
        }
        if (t == 0) {
            for (int i = tid; i < NN; i += 256) col2slot[b * NN + i] = (i < KK) ? i : -1;
            for (int i = tid; i < KK; i += 256) act_idx[b * KK + i] = i;
            return;
        }
        ull* keys = (ull*)smem;                       // 16384
        unsigned* hist = (unsigned*)(smem + 16384);   // 1024
        unsigned* suf  = (unsigned*)(smem + 17408);   // 1024
        ull* pref_sh   = (ull*)(smem + 18432);
        int* need_sh   = (int*)(smem + 18440);
        unsigned* ccnt = (unsigned*)(smem + 18444);
        if (tid == 0) *ccnt = 0;
        for (int i = tid; i < NN; i += 256) {
            keys[i] = ((ull)enc_f(gate[b * NN + i]) << 11) | (unsigned)(NN - 1 - i);
            col2slot[b * NN + i] = -1;
        }
        ull prefix = 0, pmask = 0;
        int need = KK;
        for (int shift = 40; shift >= 0; shift -= 8) {
            hist[tid] = 0;
            __syncthreads();
            for (int i = tid; i < NN; i += 256) {
                ull k = keys[i];
                if ((k & pmask) == prefix)
                    atomicAdd(&hist[(unsigned)((k >> shift) & 255)], 1u);
            }
            __syncthreads();
            suf[tid] = hist[tid];
            __syncthreads();
            for (int s = 1; s < 256; s <<= 1) {       // suffix sum
                unsigned v = (tid + s < 256) ? suf[tid + s] : 0u;
                __syncthreads();
                suf[tid] += v;
                __syncthreads();
            }
            {
                unsigned here = suf[tid];
                unsigned above = (tid == 255) ? 0u : suf[tid + 1];
                if (here >= (unsigned)need && above < (unsigned)need) {
                    *pref_sh = prefix | ((ull)tid << shift);
                    *need_sh = need - (int)above;
                }
            }
            __syncthreads();
            prefix = *pref_sh; need = *need_sh; pmask |= (0xFFull << shift);
            __syncthreads();
        }
        for (int i = tid; i < NN; i += 256) {
            ull k = keys[i];
            if (k >= prefix) {
                unsigned p = atomicAdd(ccnt, 1u);
                int n = NN - 1 - (int)(k & 2047ull);
                act_idx[b * KK + p] = n;
                col2slot[b * NN + n] = (int)p;
            }
        }
    } else {
        // out(t-1): merge flash-pool partials + rmsnorm + W_out
        if (t == 0) return;
        int b = blk - 2;
        float* pn = (float*)(smem + 20480);
        if (tid < 64) {
            int d = tid;
            float gm = -1e30f;
            for (int i = 0; i < 64; i++) gm = fmaxf(gm, pmax[b * 64 + i]);
            float s = 0.f, v = 0.f;
            for (int i = 0; i < 64; i++) {
                float e = __expf(pmax[b * 64 + i] - gm);
                s += psum[b * 64 + i] * e;
                v += ppool[(b * 64 + i) * 64 + d] * e;
            }
            float val = v / s;
            float ss = wave_sum(val * val);
            float rs = rsqrtf(ss * (1.0f / DS) + 1e-6f);
            pn[d] = onw[d] * val * rs;
        }
        __syncthreads();
        {
            int o = tid;
            const float* wr = W_out + o * DS;
            float a = 0.f;
#pragma unroll
            for (int d = 0; d < DS; d++) a += pn[d] * wr[d];
            out[(b * TT + (t - 1)) * DI + o] = a;
        }
    }
}

// ---------------------------------------------------------------- K2a: rmsnorm -> z -> g -> u
// 256 blocks = 16 col-groups x 16 out-groups (16 u-rows each).
__global__ __launch_bounds__(256) void k_core_a(
    const float* __restrict__ h, const float* __restrict__ xproj,
    const int* __restrict__ act_idx, const float* __restrict__ norm_w,
    const float* __restrict__ Wg, float* __restrict__ u_g)
{
    __shared__ float zt[128 * 64];        // [d][c] 32 KB
    __shared__ float ssq[4 * 64];
    __shared__ float rsb[64];
    int cg = blockIdx.x >> 4;             // 0..15
    int og = blockIdx.x & 15;             // 0..15
    int tid = threadIdx.x;
    int c = tid & 63;
    int seg = __builtin_amdgcn_readfirstlane(tid >> 6);
    int b = cg >> 3;
    int sbase = (cg & 7) * 64;
    int n = act_idx[b * KK + sbase + c];
    float vals[32];
    float sq = 0.f;
    if (seg < 2) {
        const float* hp = h + ((size_t)(b * NN + n)) * DS + seg * 32;
#pragma unroll
        for (int i = 0; i < 32; i++) { float v = hp[i]; vals[i] = v; sq += v * v; }
    } else {
        const float* xp = xproj + b * DS + (seg - 2) * 32;
#pragma unroll
        for (int i = 0; i < 32; i++) { float v = xp[i]; vals[i] = v; sq += v * v; }
    }
    ssq[seg * 64 + c] = sq;
    __syncthreads();
    if (tid < 64) {
        float s = ssq[tid] + ssq[64 + tid] + ssq[128 + tid] + ssq[192 + tid];
        rsb[tid] = rsqrtf(s * (1.0f / DCAT) + 1e-6f);
    }
    __syncthreads();
    {
        float rs = rsb[c];
#pragma unroll
        for (int i = 0; i < 32; i++) {
            int d = seg * 32 + i;
            zt[d * 64 + c] = norm_w[d] * vals[i] * rs;
        }
    }
    __syncthreads();
    float z[128];
#pragma unroll
    for (int d = 0; d < 128; d++) z[d] = zt[d * 64 + c];
    int rbase = og * 16 + seg * 4;
    float ga[4];
#pragma unroll
    for (int r = 0; r < 4; r++) {
        const float* wr = Wg + (rbase + r) * DCAT;        // uniform -> s_load
        float acc = 0.f;
#pragma unroll
        for (int d = 0; d < 128; d++) acc += z[d] * wr[d];
        ga[r] = acc;
    }
    int gcol = cg * 64 + c;
#pragma unroll
    for (int r = 0; r < 4; r++) {
        const float* wr = Wg + (256 + rbase + r) * DCAT;
        float bacc = 0.f;
#pragma unroll
        for (int d = 0; d < 128; d++) bacc += z[d] * wr[d];
        float uu = ga[r] * (bacc / (1.f + expf(-bacc)));  // a * silu(b)
        u_g[(rbase + r) * 1024 + gcol] = uu;              // [row][gcol] coalesced
    }
}

// ---------------------------------------------------------------- K2b: h_hat partials (split-K)
__global__ __launch_bounds__(256) void k_hupd(
    const float* __restrict__ u_g, const float* __restrict__ Wout,
    float* __restrict__ part)
{
    int blk = blockIdx.x;
    int cg = blk >> 2, kc = blk & 3;
    int tid = threadIdx.x;
    int c = tid & 63, w = tid >> 6;
    int gcol = cg * 64 + c;
    float uu[64];
#pragma unroll
    for (int i = 0; i < 64; i++) uu[i] = u_g[(kc * 64 + i) * 1024 + gcol];  // coalesced
#pragma unroll
    for (int oi = 0; oi < 16; oi++) {
        int o = w * 16 + oi;
        const float* wr = Wout + o * 256 + kc * 64;       // uniform -> s_load
        float acc = 0.f;
#pragma unroll
        for (int i = 0; i < 64; i++) acc += uu[i] * wr[i];
        part[(kc * 64 + o) * 1024 + gcol] = acc;          // coalesced
    }
}

// ---------------------------------------------------------------- K2c: h update + votes + qkv
__global__ __launch_bounds__(256) void k_vqkv(
    float* __restrict__ h, const float* __restrict__ part,
    const int* __restrict__ act_idx,
    const float* __restrict__ W_vote, const float* __restrict__ attn_in_w,
    float* __restrict__ qh, float* __restrict__ kh, float* __restrict__ vh)
{
    __shared__ float hn[64 * 32];         // [d][c]
    __shared__ float vv[64 * 32];         // [d][c]
    __shared__ int an[32];
    int blk = blockIdx.x;
    int b = blk >> 4;
    int sbase = (blk & 15) * 32;
    int tid = threadIdx.x;
    int w = __builtin_amdgcn_readfirstlane(tid >> 6);
    int l = tid & 63;
    int c = l & 31, sub = l >> 5;
    if (tid < 32) an[tid] = act_idx[b * KK + sbase + tid];
    __syncthreads();
    {
        int cc = tid & 31, o0 = tid >> 5;
        int gcol = b * KK + sbase + cc;
#pragma unroll
        for (int kk = 0; kk < 8; kk++) {
            int o = o0 + kk * 8;
            float s = part[o * 1024 + gcol] + part[(64 + o) * 1024 + gcol]
                    + part[(128 + o) * 1024 + gcol] + part[(192 + o) * 1024 + gcol];
            size_t hidx = ((size_t)(b * NN + an[cc])) * DS + o;
            float nh = h[hidx] + s;
            h[hidx] = nh;
            hn[o * 32 + cc] = nh;
        }
    }
    __syncthreads();
    float hh[32];
#pragma unroll
    for (int i = 0; i < 32; i++) hh[i] = hn[(sub * 32 + i) * 32 + c];
#pragma unroll 4
    for (int oi = 0; oi < 16; oi++) {
        int o = w * 16 + oi;
        const float* wr = W_vote + o * 64 + sub * 32;     // uniform
        float a = 0.f;
#pragma unroll
        for (int i = 0; i < 32; i++) a += hh[i] * wr[i];
        a += __shfl_xor(a, 32);
        if (sub == 0) vv[o * 32 + c] = a;
    }
    __syncthreads();
    float vq[32];
#pragma unroll
    for (int i = 0; i < 32; i++) vq[i] = vv[(sub * 32 + i) * 32 + c];
    int slot = sbase + c;
#pragma unroll 4
    for (int oi = 0; oi < 48; oi++) {
        int r = w * 48 + oi;
        const float* wr = attn_in_w + r * 64 + sub * 32;  // uniform
        float a = 0.f;
#pragma unroll
        for (int i = 0; i < 32; i++) a += vq[i] * wr[i];
        a += __shfl_xor(a, 32);
        if (sub == 0) {
            if (r < 64) {
                qh[((b * HH + (r >> 4)) * KK + slot) * HD + (r & 15)] = a;
            } else if (r < 128) {
                int rr = r - 64;
                kh[((b * HH + (rr >> 4)) * HD + (rr & 15)) * KK + slot] = a;  // [hd][slot]
            } else {
                int rr = r - 128;
                vh[((b * HH + (rr >> 4)) * HD + (rr & 15)) * KK + slot] = a;  // [hd][slot]
            }
        }
    }
}

// ---------------------------------------------------------------- K3: attention for active queries
__global__ __launch_bounds__(256) void k_attn(
    const float* __restrict__ qh, const float* __restrict__ kh,
    const float* __restrict__ vh, float* __restrict__ m_raw)
{
    int wave = threadIdx.x >> 6, lane = threadIdx.x & 63;
    int task = blockIdx.x * 4 + wave;
    int qs = task & (KK - 1);
    int bh = task >> 9;
    const float* qp = qh + (bh * KK + qs) * HD;
    float q[HD];
#pragma unroll
    for (int d = 0; d < HD; d++) q[d] = qp[d];
    const float* kp = kh + bh * HD * KK;
    const float* vp = vh + bh * HD * KK;
    float lg[8]; float mx = -1e30f;
#pragma unroll
    for (int i = 0; i < 8; i++) {
        int slot = i * 64 + lane;
        float a = 0.f;
#pragma unroll
        for (int d = 0; d < HD; d++) a += q[d] * kp[d * KK + slot];
        lg[i] = a * 0.25f;
        mx = fmaxf(mx, lg[i]);
    }
    mx = wave_max(mx);
    float p[8]; float sum = 0.f;
#pragma unroll
    for (int i = 0; i < 8; i++) { p[i] = __expf(lg[i] - mx); sum += p[i]; }
    sum = wave_sum(sum);
    float inv = 1.0f / sum;
    float acc[HD];
#pragma unroll
    for (int d = 0; d < HD; d++) acc[d] = 0.f;
#pragma unroll
    for (int i = 0; i < 8; i++) {
        int slot = i * 64 + lane;
        float pi = p[i];
#pragma unroll
        for (int d = 0; d < HD; d++) acc[d] += pi * vp[d * KK + slot];
    }
#pragma unroll
    for (int d = 0; d < HD; d++) acc[d] = wave_sum(acc[d]) * inv;
    if (lane == 0) {
        int b = bh >> 2, head = bh & 3;
#pragma unroll
        for (int d = 0; d < HD; d++)
            m_raw[(b * DV + head * HD + d) * KK + qs] = acc[d];
    }
}

// ---------------------------------------------------------------- K4: FiLM v2
// blocks 0..31: active columns (32 slots each, split dot-products);
// blocks 32..33: mean message -> fsm/fshm for inactive columns.
__global__ __launch_bounds__(256) void k_film2(
    float* __restrict__ h, const int* __restrict__ act_idx,
    const float* __restrict__ m_raw, const float* __restrict__ vh,
    const float* __restrict__ attn_out_w, const float* __restrict__ Wfs,
    const float* __restrict__ Wfsh, float* __restrict__ fsm, float* __restrict__ fshm)
{
    __shared__ char smem[33152];
    int blk = blockIdx.x;
    int tid = threadIdx.x;
    if (blk < 32) {
        float* mt  = (float*)smem;              // [64][32] 8192
        float* mot = (float*)(smem + 8192);     // [64][32] 8192
        float* sct = (float*)(smem + 16384);    // [32][65] 8320
        float* sht = (float*)(smem + 24704);    // [32][65] 8320
        int* an    = (int*)(smem + 33024);      // 128
        int b = blk >> 4;
        int sbase = (blk & 15) * 32;
        int w = __builtin_amdgcn_readfirstlane(tid >> 6);
        int lane = tid & 63;
        int s = lane & 31, half = lane >> 5;
        if (tid < 32) an[tid] = act_idx[b * KK + sbase + tid];
        for (int idx = tid; idx < 2048; idx += 256) {
            int d = idx >> 5, ss = idx & 31;
            mt[d * 32 + ss] = m_raw[(b * DV + d) * KK + sbase + ss];
        }
        __syncthreads();
#pragma unroll 4
        for (int oi = 0; oi < 16; oi++) {
            int o = w * 16 + oi;
            const float* wr = attn_out_w + o * DV + half * 32;   // uniform
            float a = 0.f;
#pragma unroll
            for (int e = 0; e < 32; e++) a += mt[(half * 32 + e) * 32 + s] * wr[e];
            a += __shfl_xor(a, 32);
            if (half == 0) mot[o * 32 + s] = a;
        }
        __syncthreads();
#pragma unroll 4
        for (int oi = 0; oi < 16; oi++) {
            int o = w * 16 + oi;
            const float* ws_ = Wfs + o * DV + half * 32;
            const float* wh_ = Wfsh + o * DV + half * 32;
            float sc = 0.f, sh = 0.f;
#pragma unroll
            for (int e = 0; e < 32; e++) {
                float zz = mot[(half * 32 + e) * 32 + s];
                sc += ws_[e] * zz; sh += wh_[e] * zz;
            }
            sc += __shfl_xor(sc, 32); sh += __shfl_xor(sh, 32);
            if (half == 0) { sct[s * 65 + o] = tanhf(sc); sht[s * 65 + o] = sh; }
        }
        __syncthreads();
        for (int idx = tid; idx < 2048; idx += 256) {
            int o = idx & 63, ss = idx >> 6;
            size_t hix = ((size_t)(b * NN + an[ss])) * DS + o;
            h[hix] = h[hix] * (1.f + sct[ss * 65 + o]) + sht[ss * 65 + o];
        }
    } else {
        int b = blk - 32;
        float* partm = (float*)smem;            // 1024
        float* mr = (float*)(smem + 1024);      // 256
        float* mo2 = (float*)(smem + 1280);     // 256
        int w = tid >> 6, lane = tid & 63;
        float macc[64];
#pragma unroll
        for (int d = 0; d < 64; d++) macc[d] = 0.f;
        for (int s = tid; s < KK; s += 256) {
#pragma unroll
            for (int d = 0; d < 64; d++) macc[d] += vh[(b * DV + d) * KK + s];
        }
#pragma unroll
        for (int d = 0; d < 64; d++) macc[d] = wave_sum(macc[d]);
        if (lane == 0) {
#pragma unroll
            for (int d = 0; d < 64; d++) partm[w * 64 + d] = macc[d];
        }
        __syncthreads();
        if (tid < 64)
            mr[tid] = (partm[tid] + partm[64 + tid] + partm[128 + tid] + partm[192 + tid]) * (1.0f / KK);
        __syncthreads();
        if (tid < 64) {
            const float* wo = attn_out_w + tid * DV;
            float a = 0.f;
#pragma unroll
            for (int e = 0; e < 64; e++) a += mr[e] * wo[e];
            mo2[tid] = a;
        }
        __syncthreads();
        if (tid < 64) {
            const float* ws_ = Wfs + tid * DV;
            const float* wh_ = Wfsh + tid * DV;
            float sc = 0.f, sh = 0.f;
#pragma unroll
            for (int e = 0; e < 64; e++) { float zz = mo2[e]; sc += ws_[e] * zz; sh += wh_[e] * zz; }
            fsm[b * DS + tid] = tanhf(sc);
            fshm[b * DS + tid] = sh;
        }
    }
}

// ---------------------------------------------------------------- K5: inactive FiLM + gate + flash pool partials
__global__ __launch_bounds__(256) void k_pool2(
    float* __restrict__ h, const int* __restrict__ col2slot,
    const float* __restrict__ fsm, const float* __restrict__ fshm,
    const float* __restrict__ query, const float* __restrict__ W_gate,
    float* __restrict__ gate, float* __restrict__ ppool,
    float* __restrict__ psum, float* __restrict__ pmax)
{
    __shared__ float wvecs[4][64];
    __shared__ float wms[4], wss[4];
    int blk = blockIdx.x;
    int b = blk >> 6;
    int base = (blk & 63) * 32;
    int tid = threadIdx.x;
    int w = tid >> 6, lane = tid & 63;
    float fs = fsm[b * DS + lane], fh = fshm[b * DS + lane];
    float qv = query[lane] * 0.125f, wg = W_gate[lane];
    float wm = -1e30f, sw = 0.f, vec = 0.f;
#pragma unroll
    for (int ci = 0; ci < 8; ci++) {
        int n = base + w * 8 + ci;
        size_t idx = ((size_t)(b * NN + n)) * DS + lane;
        float hv = h[idx];
        int slot = col2slot[b * NN + n];
        if (slot < 0) { hv = hv * (1.f + fs) + fh; h[idx] = hv; }
        float lg = wave_sum(qv * hv);
        float gt = wave_sum(wg * hv);
        if (lane == 0) gate[b * NN + n] = gt;
        float nm = fmaxf(wm, lg);
        float scale = __expf(wm - nm);
        float e = __expf(lg - nm);
        sw = sw * scale + e;
        vec = vec * scale + e * hv;
        wm = nm;
    }
    wvecs[w][lane] = vec;
    if (lane == 0) { wms[w] = wm; wss[w] = sw; }
    __syncthreads();
    if (tid < 64) {
        float m4 = fmaxf(fmaxf(wms[0], wms[1]), fmaxf(wms[2], wms[3]));
        float s = 0.f, v = 0.f;
#pragma unroll
        for (int ww = 0; ww < 4; ww++) {
            float e = __expf(wms[ww] - m4);
            s += wss[ww] * e;
            v += wvecs[ww][tid] * e;
        }
        ppool[blk * 64 + tid] = v;
        if (tid == 0) { psum[blk] = s; pmax[blk] = m4; }
    }
}

// ----------------------------------------------------------------
extern "C" void kernel_launch(void* const* d_in, const int* in_sizes, int n_in,
                              void* d_out, int out_size, void* d_ws, size_t ws_size,
                              hipStream_t stream)
{
    const float* x          = (const float*)d_in[0];
    const float* W_in       = (const float*)d_in[1];
    const float* core_norm_w= (const float*)d_in[2];
    const float* core_Wg    = (const float*)d_in[3];
    const float* core_Wout  = (const float*)d_in[4];
    const float* W_gate     = (const float*)d_in[5];
    const float* W_vote     = (const float*)d_in[6];
    const float* attn_in_w  = (const float*)d_in[7];
    const float* attn_out_w = (const float*)d_in[8];
    const float* Wfs        = (const float*)d_in[9];
    const float* Wfsh       = (const float*)d_in[10];
    const float* query      = (const float*)d_in[11];
    const float* onw        = (const float*)d_in[12];
    const float* W_out      = (const float*)d_in[13];
    float* out = (float*)d_out;

    float* ws = (float*)d_ws;
    float* h        = ws;                              // 262144
    float* gate     = h + (size_t)BB * NN * DS;        // 4096
    float* xproj    = gate + BB * NN;                  // 128
    int*   col2slot = (int*)(xproj + BB * DS);         // 4096
    int*   act_idx  = col2slot + BB * NN;              // 1024
    float* u_g      = (float*)(act_idx + BB * KK);     // 262144
    float* part     = u_g + 256 * 1024;                // 262144
    float* qh       = part + 256 * 1024;               // 65536
    float* kh       = qh + BB * HH * KK * HD;
    float* vh       = kh + BB * HH * KK * HD;
    float* m_raw    = vh + BB * HH * KK * HD;          // 65536
    float* fsm      = m_raw + BB * DV * KK;            // 128
    float* fshm     = fsm + BB * DS;                   // 128
    float* ppool    = fshm + BB * DS;                  // 8192
    float* psum     = ppool + 128 * 64;                // 128
    float* pmax     = psum + 128;                      // 128

    // zero h and gate (adjacent) in one memset
    hipMemsetAsync(h, 0, ((size_t)BB * NN * DS + BB * NN) * sizeof(float), stream);

    for (int t = 0; t < TT; t++) {
        k_head<<<4, 256, 0, stream>>>(gate, x, W_in, col2slot, act_idx, xproj,
                                      ppool, psum, pmax, onw, W_out, out, t);
        k_core_a<<<256, 256, 0, stream>>>(h, xproj, act_idx, core_norm_w, core_Wg, u_g);
        k_hupd<<<64, 256, 0, stream>>>(u_g, core_Wout, part);
        k_vqkv<<<32, 256, 0, stream>>>(h, part, act_idx, W_vote, attn_in_w, qh, kh, vh);
        k_attn<<<BB * HH * KK / 4, 256, 0, stream>>>(qh, kh, vh, m_raw);
        k_film2<<<34, 256, 0, stream>>>(h, act_idx, m_raw, vh, attn_out_w, Wfs, Wfsh, fsm, fshm);
        k_pool2<<<128, 256, 0, stream>>>(h, col2slot, fsm, fshm, query, W_gate, gate, ppool, psum, pmax);
    }
    k_head<<<4, 256, 0, stream>>>(gate, x, W_in, col2slot, act_idx, xproj,
                                  ppool, psum, pmax, onw, W_out, out, TT);
}

// Round 7
// 412.736 us; speedup vs baseline: 7.5078x; 1.0230x over previous
//
#include <hip/hip_runtime.h>
#include <hip/hip_bf16.h>

// Model dims
#define NN 2048
#define DS 64
#define DI 256
#define DV 64
#define KK 512
#define HH 4
#define HD 16
#define BB 2
#define TT 4
#define DCAT 192

typedef unsigned long long ull;

__device__ __forceinline__ float wave_sum(float v) {
#pragma unroll
    for (int o = 32; o > 0; o >>= 1) v += __shfl_xor(v, o);
    return v;
}
__device__ __forceinline__ float wave_max(float v) {
#pragma unroll
    for (int o = 32; o > 0; o >>= 1) v = fmaxf(v, __shfl_xor(v, o));
    return v;
}
__device__ __forceinline__ unsigned enc_f(float f) {
    unsigned u = __float_as_uint(f);
    return (u & 0x80000000u) ? ~u : (u | 0x80000000u);
}

// ---------------------------------------------------------------- K1: head kernel
// blocks 0-1: radix-select top-k (t<TT) + xproj(t).  blocks 2-3: out(t-1).
__global__ __launch_bounds__(256) void k_head(
    const float* __restrict__ gate, const float* __restrict__ x,
    const float* __restrict__ W_in, int* __restrict__ col2slot,
    int* __restrict__ act_idx, float* __restrict__ xproj,
    const float* __restrict__ ppool, const float* __restrict__ psum,
    const float* __restrict__ pmax, const float* __restrict__ onw,
    const float* __restrict__ W_out, float* __restrict__ out, int t)
{
    __shared__ char smem[20992];
    int blk = blockIdx.x, tid = threadIdx.x;
    if (blk < 2) {
        if (t >= TT) return;
        int b = blk;
        {   // xproj: x_t @ W_in.T  (4 lanes per output row)
            int r = tid >> 2, q = tid & 3;
            const float* xp = x + (b * TT + t) * DI + q * 64;
            const float* wr = W_in + r * DI + q * 64;
            float a = 0.f;
#pragma unroll
            for (int i = 0; i < 64; i++) a += xp[i] * wr[i];
            a += __shfl_xor(a, 1); a += __shfl_xor(a, 2);
            if (q == 0) xproj[b * DS + r] = a;
        }
        if (t == 0) {
            for (int i = tid; i < NN; i += 256) col2slot[b * NN + i] = (i < KK) ? i : -1;
            for (int i = tid; i < KK; i += 256) act_idx[b * KK + i] = i;
            return;
        }
        ull* keys = (ull*)smem;                       // 16384
        unsigned* hist = (unsigned*)(smem + 16384);   // 1024
        unsigned* suf  = (unsigned*)(smem + 17408);   // 1024
        ull* pref_sh   = (ull*)(smem + 18432);
        int* need_sh   = (int*)(smem + 18440);
        unsigned* ccnt = (unsigned*)(smem + 18444);
        if (tid == 0) *ccnt = 0;
        for (int i = tid; i < NN; i += 256) {
            keys[i] = ((ull)enc_f(gate[b * NN + i]) << 11) | (unsigned)(NN - 1 - i);
            col2slot[b * NN + i] = -1;
        }
        ull prefix = 0, pmask = 0;
        int need = KK;
        for (int shift = 40; shift >= 0; shift -= 8) {
            hist[tid] = 0;
            __syncthreads();
            for (int i = tid; i < NN; i += 256) {
                ull k = keys[i];
                if ((k & pmask) == prefix)
                    atomicAdd(&hist[(unsigned)((k >> shift) & 255)], 1u);
            }
            __syncthreads();
            suf[tid] = hist[tid];
            __syncthreads();
            for (int s = 1; s < 256; s <<= 1) {       // suffix sum
                unsigned v = (tid + s < 256) ? suf[tid + s] : 0u;
                __syncthreads();
                suf[tid] += v;
                __syncthreads();
            }
            {
                unsigned here = suf[tid];
                unsigned above = (tid == 255) ? 0u : suf[tid + 1];
                if (here >= (unsigned)need && above < (unsigned)need) {
                    *pref_sh = prefix | ((ull)tid << shift);
                    *need_sh = need - (int)above;
                }
            }
            __syncthreads();
            prefix = *pref_sh; need = *need_sh; pmask |= (0xFFull << shift);
            __syncthreads();
        }
        for (int i = tid; i < NN; i += 256) {
            ull k = keys[i];
            if (k >= prefix) {
                unsigned p = atomicAdd(ccnt, 1u);
                int n = NN - 1 - (int)(k & 2047ull);
                act_idx[b * KK + p] = n;
                col2slot[b * NN + n] = (int)p;
            }
        }
    } else {
        // out(t-1): merge flash-pool partials + rmsnorm + W_out
        if (t == 0) return;
        int b = blk - 2;
        float* pn = (float*)(smem + 20480);
        if (tid < 64) {
            int d = tid;
            float gm = -1e30f;
            for (int i = 0; i < 64; i++) gm = fmaxf(gm, pmax[b * 64 + i]);
            float s = 0.f, v = 0.f;
            for (int i = 0; i < 64; i++) {
                float e = __expf(pmax[b * 64 + i] - gm);
                s += psum[b * 64 + i] * e;
                v += ppool[(b * 64 + i) * 64 + d] * e;
            }
            float val = v / s;
            float ss = wave_sum(val * val);
            float rs = rsqrtf(ss * (1.0f / DS) + 1e-6f);
            pn[d] = onw[d] * val * rs;
        }
        __syncthreads();
        {
            int o = tid;
            const float* wr = W_out + o * DS;
            float a = 0.f;
#pragma unroll
            for (int d = 0; d < DS; d++) a += pn[d] * wr[d];
            out[(b * TT + (t - 1)) * DI + o] = a;
        }
    }
}

// ---------------------------------------------------------------- K2a: rmsnorm -> z -> g -> u
__global__ __launch_bounds__(256) void k_core_a(
    const float* __restrict__ h, const float* __restrict__ xproj,
    const int* __restrict__ act_idx, const float* __restrict__ norm_w,
    const float* __restrict__ Wg, float* __restrict__ u_g)
{
    __shared__ float zt[128 * 64];        // [d][c] 32 KB
    __shared__ float ssq[4 * 64];
    __shared__ float rsb[64];
    int cg = blockIdx.x >> 4;             // 0..15
    int og = blockIdx.x & 15;             // 0..15
    int tid = threadIdx.x;
    int c = tid & 63;
    int seg = __builtin_amdgcn_readfirstlane(tid >> 6);
    int b = cg >> 3;
    int sbase = (cg & 7) * 64;
    int n = act_idx[b * KK + sbase + c];
    float vals[32];
    float sq = 0.f;
    if (seg < 2) {
        const float* hp = h + ((size_t)(b * NN + n)) * DS + seg * 32;
#pragma unroll
        for (int i = 0; i < 32; i++) { float v = hp[i]; vals[i] = v; sq += v * v; }
    } else {
        const float* xp = xproj + b * DS + (seg - 2) * 32;
#pragma unroll
        for (int i = 0; i < 32; i++) { float v = xp[i]; vals[i] = v; sq += v * v; }
    }
    ssq[seg * 64 + c] = sq;
    __syncthreads();
    if (tid < 64) {
        float s = ssq[tid] + ssq[64 + tid] + ssq[128 + tid] + ssq[192 + tid];
        rsb[tid] = rsqrtf(s * (1.0f / DCAT) + 1e-6f);
    }
    __syncthreads();
    {
        float rs = rsb[c];
#pragma unroll
        for (int i = 0; i < 32; i++) {
            int d = seg * 32 + i;
            zt[d * 64 + c] = norm_w[d] * vals[i] * rs;
        }
    }
    __syncthreads();
    float z[128];
#pragma unroll
    for (int d = 0; d < 128; d++) z[d] = zt[d * 64 + c];
    int rbase = og * 16 + seg * 4;
    float ga[4];
#pragma unroll
    for (int r = 0; r < 4; r++) {
        const float* wr = Wg + (rbase + r) * DCAT;        // uniform -> s_load
        float acc = 0.f;
#pragma unroll
        for (int d = 0; d < 128; d++) acc += z[d] * wr[d];
        ga[r] = acc;
    }
    int gcol = cg * 64 + c;
#pragma unroll
    for (int r = 0; r < 4; r++) {
        const float* wr = Wg + (256 + rbase + r) * DCAT;
        float bacc = 0.f;
#pragma unroll
        for (int d = 0; d < 128; d++) bacc += z[d] * wr[d];
        float uu = ga[r] * (bacc / (1.f + expf(-bacc)));  // a * silu(b)
        u_g[(rbase + r) * 1024 + gcol] = uu;              // [row][gcol] coalesced
    }
}

// ---------------------------------------------------------------- K2b: h_hat partials (split-K)
// 64 blocks = 16 col-groups x 4 K-chunks. Output TRANSPOSED to part[gcol][j]
// via LDS so the consumer can read lane->o coalesced.
__global__ __launch_bounds__(256) void k_hupd(
    const float* __restrict__ u_g, const float* __restrict__ Wout,
    float* __restrict__ part)
{
    __shared__ float tile[64 * 65];       // [o][c] pad-65, 16.6 KB
    int blk = blockIdx.x;
    int cg = blk >> 2, kc = blk & 3;
    int tid = threadIdx.x;
    int c = tid & 63, w = tid >> 6;
    int gcolbase = cg * 64;
    float uu[64];
#pragma unroll
    for (int i = 0; i < 64; i++) uu[i] = u_g[(kc * 64 + i) * 1024 + gcolbase + c];  // coalesced
#pragma unroll
    for (int oi = 0; oi < 16; oi++) {
        int o = w * 16 + oi;
        const float* wr = Wout + o * 256 + kc * 64;       // uniform -> s_load
        float acc = 0.f;
#pragma unroll
        for (int i = 0; i < 64; i++) acc += uu[i] * wr[i];
        tile[o * 65 + c] = acc;
    }
    __syncthreads();
#pragma unroll
    for (int k = 0; k < 16; k++) {
        int flat = k * 256 + tid;
        int gl = flat >> 6, oo = flat & 63;
        part[(size_t)(gcolbase + gl) * 256 + kc * 64 + oo] = tile[oo * 65 + gl];  // coalesced
    }
}

// ---------------------------------------------------------------- K2c: h update + votes + qkv (coalesced phase A)
__global__ __launch_bounds__(256) void k_vqkv(
    float* __restrict__ h, const float* __restrict__ part,
    const int* __restrict__ act_idx,
    const float* __restrict__ W_vote, const float* __restrict__ attn_in_w,
    float* __restrict__ qh, float* __restrict__ kh, float* __restrict__ vh)
{
    __shared__ float hn[64 * 33];         // [d][c] pad-33
    __shared__ float vv[64 * 33];         // [d][c] pad-33
    __shared__ int an[32];
    int blk = blockIdx.x;
    int b = blk >> 4;
    int sbase = (blk & 15) * 32;
    int tid = threadIdx.x;
    int w = __builtin_amdgcn_readfirstlane(tid >> 6);
    int l = tid & 63;
    int c = l & 31, sub = l >> 5;
    if (tid < 32) an[tid] = act_idx[b * KK + sbase + tid];
    __syncthreads();
    // phase A: reduce 4 K-chunk partials + h update, all coalesced (lane -> o)
    {
        int o = tid & 63;
#pragma unroll
        for (int k = 0; k < 8; k++) {
            int s = (tid >> 6) + k * 4;                   // wave-uniform slot
            const float* pp = part + (size_t)(b * KK + sbase + s) * 256 + o;
            float sum = pp[0] + pp[64] + pp[128] + pp[192];
            size_t hidx = ((size_t)(b * NN + an[s])) * DS + o;
            float nh = h[hidx] + sum;                     // coalesced 256B row
            h[hidx] = nh;
            hn[o * 33 + s] = nh;
        }
    }
    __syncthreads();
    // phase B: votes v = W_vote @ h_new
    float hh[32];
#pragma unroll
    for (int i = 0; i < 32; i++) hh[i] = hn[(sub * 32 + i) * 33 + c];
#pragma unroll 4
    for (int oi = 0; oi < 16; oi++) {
        int o = w * 16 + oi;
        const float* wr = W_vote + o * 64 + sub * 32;     // uniform
        float a = 0.f;
#pragma unroll
        for (int i = 0; i < 32; i++) a += hh[i] * wr[i];
        a += __shfl_xor(a, 32);
        if (sub == 0) vv[o * 33 + c] = a;
    }
    __syncthreads();
    // phase C: qkv = attn_in_w @ v
    float vq[32];
#pragma unroll
    for (int i = 0; i < 32; i++) vq[i] = vv[(sub * 32 + i) * 33 + c];
    int slot = sbase + c;
#pragma unroll 4
    for (int oi = 0; oi < 48; oi++) {
        int r = w * 48 + oi;
        const float* wr = attn_in_w + r * 64 + sub * 32;  // uniform
        float a = 0.f;
#pragma unroll
        for (int i = 0; i < 32; i++) a += vq[i] * wr[i];
        a += __shfl_xor(a, 32);
        if (sub == 0) {
            if (r < 64) {
                qh[((b * HH + (r >> 4)) * KK + slot) * HD + (r & 15)] = a;
            } else if (r < 128) {
                int rr = r - 64;
                kh[((b * HH + (rr >> 4)) * HD + (rr & 15)) * KK + slot] = a;  // [hd][slot]
            } else {
                int rr = r - 128;
                vh[((b * HH + (rr >> 4)) * HD + (rr & 15)) * KK + slot] = a;  // [hd][slot]
            }
        }
    }
}

// ---------------------------------------------------------------- K3: attention for active queries
__global__ __launch_bounds__(256) void k_attn(
    const float* __restrict__ qh, const float* __restrict__ kh,
    const float* __restrict__ vh, float* __restrict__ m_raw)
{
    int wave = threadIdx.x >> 6, lane = threadIdx.x & 63;
    int task = blockIdx.x * 4 + wave;
    int qs = task & (KK - 1);
    int bh = task >> 9;
    const float* qp = qh + (bh * KK + qs) * HD;
    float q[HD];
#pragma unroll
    for (int d = 0; d < HD; d++) q[d] = qp[d];
    const float* kp = kh + bh * HD * KK;
    const float* vp = vh + bh * HD * KK;
    float lg[8]; float mx = -1e30f;
#pragma unroll
    for (int i = 0; i < 8; i++) {
        int slot = i * 64 + lane;
        float a = 0.f;
#pragma unroll
        for (int d = 0; d < HD; d++) a += q[d] * kp[d * KK + slot];
        lg[i] = a * 0.25f;
        mx = fmaxf(mx, lg[i]);
    }
    mx = wave_max(mx);
    float p[8]; float sum = 0.f;
#pragma unroll
    for (int i = 0; i < 8; i++) { p[i] = __expf(lg[i] - mx); sum += p[i]; }
    sum = wave_sum(sum);
    float inv = 1.0f / sum;
    float acc[HD];
#pragma unroll
    for (int d = 0; d < HD; d++) acc[d] = 0.f;
#pragma unroll
    for (int i = 0; i < 8; i++) {
        int slot = i * 64 + lane;
        float pi = p[i];
#pragma unroll
        for (int d = 0; d < HD; d++) acc[d] += pi * vp[d * KK + slot];
    }
#pragma unroll
    for (int d = 0; d < HD; d++) acc[d] = wave_sum(acc[d]) * inv;
    if (lane == 0) {
        int b = bh >> 2, head = bh & 3;
#pragma unroll
        for (int d = 0; d < HD; d++)
            m_raw[(b * DV + head * HD + d) * KK + qs] = acc[d];
    }
}

// ---------------------------------------------------------------- K4: FiLM v2
__global__ __launch_bounds__(256) void k_film2(
    float* __restrict__ h, const int* __restrict__ act_idx,
    const float* __restrict__ m_raw, const float* __restrict__ vh,
    const float* __restrict__ attn_out_w, const float* __restrict__ Wfs,
    const float* __restrict__ Wfsh, float* __restrict__ fsm, float* __restrict__ fshm)
{
    __shared__ char smem[33152];
    int blk = blockIdx.x;
    int tid = threadIdx.x;
    if (blk < 32) {
        float* mt  = (float*)smem;              // [64][32] 8192
        float* mot = (float*)(smem + 8192);     // [64][32] 8192
        float* sct = (float*)(smem + 16384);    // [32][65] 8320
        float* sht = (float*)(smem + 24704);    // [32][65] 8320
        int* an    = (int*)(smem + 33024);      // 128
        int b = blk >> 4;
        int sbase = (blk & 15) * 32;
        int w = __builtin_amdgcn_readfirstlane(tid >> 6);
        int lane = tid & 63;
        int s = lane & 31, half = lane >> 5;
        if (tid < 32) an[tid] = act_idx[b * KK + sbase + tid];
        for (int idx = tid; idx < 2048; idx += 256) {
            int d = idx >> 5, ss = idx & 31;
            mt[d * 32 + ss] = m_raw[(b * DV + d) * KK + sbase + ss];
        }
        __syncthreads();
#pragma unroll 4
        for (int oi = 0; oi < 16; oi++) {
            int o = w * 16 + oi;
            const float* wr = attn_out_w + o * DV + half * 32;   // uniform
            float a = 0.f;
#pragma unroll
            for (int e = 0; e < 32; e++) a += mt[(half * 32 + e) * 32 + s] * wr[e];
            a += __shfl_xor(a, 32);
            if (half == 0) mot[o * 32 + s] = a;
        }
        __syncthreads();
#pragma unroll 4
        for (int oi = 0; oi < 16; oi++) {
            int o = w * 16 + oi;
            const float* ws_ = Wfs + o * DV + half * 32;
            const float* wh_ = Wfsh + o * DV + half * 32;
            float sc = 0.f, sh = 0.f;
#pragma unroll
            for (int e = 0; e < 32; e++) {
                float zz = mot[(half * 32 + e) * 32 + s];
                sc += ws_[e] * zz; sh += wh_[e] * zz;
            }
            sc += __shfl_xor(sc, 32); sh += __shfl_xor(sh, 32);
            if (half == 0) { sct[s * 65 + o] = tanhf(sc); sht[s * 65 + o] = sh; }
        }
        __syncthreads();
        for (int idx = tid; idx < 2048; idx += 256) {
            int o = idx & 63, ss = idx >> 6;
            size_t hix = ((size_t)(b * NN + an[ss])) * DS + o;
            h[hix] = h[hix] * (1.f + sct[ss * 65 + o]) + sht[ss * 65 + o];
        }
    } else {
        int b = blk - 32;
        float* partm = (float*)smem;            // 1024
        float* mr = (float*)(smem + 1024);      // 256
        float* mo2 = (float*)(smem + 1280);     // 256
        int w = tid >> 6, lane = tid & 63;
        float macc[64];
#pragma unroll
        for (int d = 0; d < 64; d++) macc[d] = 0.f;
        for (int s = tid; s < KK; s += 256) {
#pragma unroll
            for (int d = 0; d < 64; d++) macc[d] += vh[(b * DV + d) * KK + s];
        }
#pragma unroll
        for (int d = 0; d < 64; d++) macc[d] = wave_sum(macc[d]);
        if (lane == 0) {
#pragma unroll
            for (int d = 0; d < 64; d++) partm[w * 64 + d] = macc[d];
        }
        __syncthreads();
        if (tid < 64)
            mr[tid] = (partm[tid] + partm[64 + tid] + partm[128 + tid] + partm[192 + tid]) * (1.0f / KK);
        __syncthreads();
        if (tid < 64) {
            const float* wo = attn_out_w + tid * DV;
            float a = 0.f;
#pragma unroll
            for (int e = 0; e < 64; e++) a += mr[e] * wo[e];
            mo2[tid] = a;
        }
        __syncthreads();
        if (tid < 64) {
            const float* ws_ = Wfs + tid * DV;
            const float* wh_ = Wfsh + tid * DV;
            float sc = 0.f, sh = 0.f;
#pragma unroll
            for (int e = 0; e < 64; e++) { float zz = mo2[e]; sc += ws_[e] * zz; sh += wh_[e] * zz; }
            fsm[b * DS + tid] = tanhf(sc);
            fshm[b * DS + tid] = sh;
        }
    }
}

// ---------------------------------------------------------------- K5: inactive FiLM + gate + flash pool partials
__global__ __launch_bounds__(256) void k_pool2(
    float* __restrict__ h, const int* __restrict__ col2slot,
    const float* __restrict__ fsm, const float* __restrict__ fshm,
    const float* __restrict__ query, const float* __restrict__ W_gate,
    float* __restrict__ gate, float* __restrict__ ppool,
    float* __restrict__ psum, float* __restrict__ pmax)
{
    __shared__ float wvecs[4][64];
    __shared__ float wms[4], wss[4];
    int blk = blockIdx.x;
    int b = blk >> 6;
    int base = (blk & 63) * 32;
    int tid = threadIdx.x;
    int w = tid >> 6, lane = tid & 63;
    float fs = fsm[b * DS + lane], fh = fshm[b * DS + lane];
    float qv = query[lane] * 0.125f, wg = W_gate[lane];
    float wm = -1e30f, sw = 0.f, vec = 0.f;
#pragma unroll
    for (int ci = 0; ci < 8; ci++) {
        int n = base + w * 8 + ci;
        size_t idx = ((size_t)(b * NN + n)) * DS + lane;
        float hv = h[idx];
        int slot = col2slot[b * NN + n];
        if (slot < 0) { hv = hv * (1.f + fs) + fh; h[idx] = hv; }
        float lg = wave_sum(qv * hv);
        float gt = wave_sum(wg * hv);
        if (lane == 0) gate[b * NN + n] = gt;
        float nm = fmaxf(wm, lg);
        float scale = __expf(wm - nm);
        float e = __expf(lg - nm);
        sw = sw * scale + e;
        vec = vec * scale + e * hv;
        wm = nm;
    }
    wvecs[w][lane] = vec;
    if (lane == 0) { wms[w] = wm; wss[w] = sw; }
    __syncthreads();
    if (tid < 64) {
        float m4 = fmaxf(fmaxf(wms[0], wms[1]), fmaxf(wms[2], wms[3]));
        float s = 0.f, v = 0.f;
#pragma unroll
        for (int ww = 0; ww < 4; ww++) {
            float e = __expf(wms[ww] - m4);
            s += wss[ww] * e;
            v += wvecs[ww][tid] * e;
        }
        ppool[blk * 64 + tid] = v;
        if (tid == 0) { psum[blk] = s; pmax[blk] = m4; }
    }
}

// ----------------------------------------------------------------
extern "C" void kernel_launch(void* const* d_in, const int* in_sizes, int n_in,
                              void* d_out, int out_size, void* d_ws, size_t ws_size,
                              hipStream_t stream)
{
    const float* x          = (const float*)d_in[0];
    const float* W_in       = (const float*)d_in[1];
    const float* core_norm_w= (const float*)d_in[2];
    const float* core_Wg    = (const float*)d_in[3];
    const float* core_Wout  = (const float*)d_in[4];
    const float* W_gate     = (const float*)d_in[5];
    const float* W_vote     = (const float*)d_in[6];
    const float* attn_in_w  = (const float*)d_in[7];
    const float* attn_out_w = (const float*)d_in[8];
    const float* Wfs        = (const float*)d_in[9];
    const float* Wfsh       = (const float*)d_in[10];
    const float* query      = (const float*)d_in[11];
    const float* onw        = (const float*)d_in[12];
    const float* W_out      = (const float*)d_in[13];
    float* out = (float*)d_out;

    float* ws = (float*)d_ws;
    float* h        = ws;                              // 262144
    float* gate     = h + (size_t)BB * NN * DS;        // 4096
    float* xproj    = gate + BB * NN;                  // 128
    int*   col2slot = (int*)(xproj + BB * DS);         // 4096
    int*   act_idx  = col2slot + BB * NN;              // 1024
    float* u_g      = (float*)(act_idx + BB * KK);     // 262144
    float* part     = u_g + 256 * 1024;                // 262144 (part[gcol][256])
    float* qh       = part + 256 * 1024;               // 65536
    float* kh       = qh + BB * HH * KK * HD;
    float* vh       = kh + BB * HH * KK * HD;
    float* m_raw    = vh + BB * HH * KK * HD;          // 65536
    float* fsm      = m_raw + BB * DV * KK;            // 128
    float* fshm     = fsm + BB * DS;                   // 128
    float* ppool    = fshm + BB * DS;                  // 8192
    float* psum     = ppool + 128 * 64;                // 128
    float* pmax     = psum + 128;                      // 128

    // zero h and gate (adjacent) in one memset
    hipMemsetAsync(h, 0, ((size_t)BB * NN * DS + BB * NN) * sizeof(float), stream);

    for (int t = 0; t < TT; t++) {
        k_head<<<4, 256, 0, stream>>>(gate, x, W_in, col2slot, act_idx, xproj,
                                      ppool, psum, pmax, onw, W_out, out, t);
        k_core_a<<<256, 256, 0, stream>>>(h, xproj, act_idx, core_norm_w, core_Wg, u_g);
        k_hupd<<<64, 256, 0, stream>>>(u_g, core_Wout, part);
        k_vqkv<<<32, 256, 0, stream>>>(h, part, act_idx, W_vote, attn_in_w, qh, kh, vh);
        k_attn<<<BB * HH * KK / 4, 256, 0, stream>>>(qh, kh, vh, m_raw);
        k_film2<<<34, 256, 0, stream>>>(h, act_idx, m_raw, vh, attn_out_w, Wfs, Wfsh, fsm, fshm);
        k_pool2<<<128, 256, 0, stream>>>(h, col2slot, fsm, fshm, query, W_gate, gate, ppool, psum, pmax);
    }
    k_head<<<4, 256, 0, stream>>>(gate, x, W_in, col2slot, act_idx, xproj,
                                  ppool, psum, pmax, onw, W_out, out, TT);
}